// Round 4
// baseline (161.330 us; speedup 1.0000x reference)
//
#include <hip/hip_runtime.h>

#define IMG_H 8192
#define IMG_W 8192
#define XG    (IMG_W / 8)   // 1024 x-groups per row (8 px each)
#define YG    (IMG_H / 4)   // 2048 y-groups (4 rows each)

typedef float floatx4 __attribute__((ext_vector_type(4)));

// Each thread computes an 8-wide x 4-tall output tile.
// Interior: 24 independent loads hoisted up front (6 rows x {left, vec4, vec4, right}),
// 96 FMAs, 8 nontemporal float4 stores. launch_bounds(256,4) -> VGPR cap 128 so the
// allocator keeps the whole load batch in flight (R3's cap of 32 VGPR serialized it).
__global__ __launch_bounds__(256, 4) void conv3x3_kernel(const float* __restrict__ img,
                                                         const float* __restrict__ ker,
                                                         float* __restrict__ out) {
    const int tid = blockIdx.x * 256 + threadIdx.x;
    const int xg  = tid & (XG - 1);
    const int yg  = tid >> 10;           // tid / 1024
    const int x0  = xg << 3;
    const int y0  = yg << 2;

    const float w00 = ker[0], w01 = ker[1], w02 = ker[2];
    const float w10 = ker[3], w11 = ker[4], w12 = ker[5];
    const float w20 = ker[6], w21 = ker[7], w22 = ker[8];

    const bool interior = (y0 >= 1) & (y0 + 4 <= IMG_H - 1) & (x0 >= 8) & (x0 + 8 <= IMG_W - 1);
    if (interior) {
        // Hoist all 24 loads — independent, maximizes memory-level parallelism.
        floatx4 va[6], vb[6];
        float   l[6], r[6];
        const float* p = img + (size_t)(y0 - 1) * IMG_W + x0;
        #pragma unroll
        for (int i = 0; i < 6; ++i) {
            va[i] = *(const floatx4*)p;
            vb[i] = *(const floatx4*)(p + 4);
            l[i]  = p[-1];
            r[i]  = p[8];
            p += IMG_W;
        }
        #pragma unroll
        for (int oy = 0; oy < 4; ++oy) {
            float acc[8];
            #pragma unroll
            for (int j = 0; j < 8; ++j) acc[j] = 0.f;
            #pragma unroll
            for (int i = 0; i < 3; ++i) {
                const int ri = oy + i;
                const float wa = (i == 0) ? w00 : (i == 1) ? w10 : w20;
                const float wb = (i == 0) ? w01 : (i == 1) ? w11 : w21;
                const float wc = (i == 0) ? w02 : (i == 1) ? w12 : w22;
                // 10 inputs for this row: l, va.xyzw, vb.xyzw, r
                float in[10];
                in[0] = l[ri];
                in[1] = va[ri].x; in[2] = va[ri].y; in[3] = va[ri].z; in[4] = va[ri].w;
                in[5] = vb[ri].x; in[6] = vb[ri].y; in[7] = vb[ri].z; in[8] = vb[ri].w;
                in[9] = r[ri];
                #pragma unroll
                for (int j = 0; j < 8; ++j)
                    acc[j] += wa * in[j] + wb * in[j + 1] + wc * in[j + 2];
            }
            floatx4 r0 = {acc[0], acc[1], acc[2], acc[3]};
            floatx4 r1 = {acc[4], acc[5], acc[6], acc[7]};
            float* orow = out + (size_t)(y0 + oy) * IMG_W + x0;
            // Output is write-once: bypass caches, keep L3 for the image.
            __builtin_nontemporal_store(r0, (floatx4*)orow);
            __builtin_nontemporal_store(r1, (floatx4*)(orow + 4));
        }
    } else {
        // Boundary tiles (edge strips only): safe scalar path with zero padding.
        #pragma unroll
        for (int oy = 0; oy < 4; ++oy) {
            const int y = y0 + oy;
            float acc[8];
            #pragma unroll
            for (int j = 0; j < 8; ++j) {
                const int x = x0 + j;
                float s = 0.f;
                for (int di = -1; di <= 1; ++di) {
                    const int yy = y + di;
                    if (yy < 0 || yy >= IMG_H) continue;
                    for (int dj = -1; dj <= 1; ++dj) {
                        const int xx = x + dj;
                        if (xx < 0 || xx >= IMG_W) continue;
                        s += ker[(di + 1) * 3 + (dj + 1)] * img[(size_t)yy * IMG_W + xx];
                    }
                }
                acc[j] = s;
            }
            floatx4 r0 = {acc[0], acc[1], acc[2], acc[3]};
            floatx4 r1 = {acc[4], acc[5], acc[6], acc[7]};
            float* orow = out + (size_t)y * IMG_W + x0;
            *(floatx4*)orow       = r0;
            *(floatx4*)(orow + 4) = r1;
        }
    }
}

extern "C" void kernel_launch(void* const* d_in, const int* in_sizes, int n_in,
                              void* d_out, int out_size, void* d_ws, size_t ws_size,
                              hipStream_t stream) {
    const float* img = (const float*)d_in[0];
    const float* ker = (const float*)d_in[1];
    float* out = (float*)d_out;

    const int total_threads = XG * YG;       // 2,097,152
    const int block = 256;
    const int grid  = total_threads / block; // 8,192
    conv3x3_kernel<<<grid, block, 0, stream>>>(img, ker, out);
}

// Round 5
// 90.224 us; speedup vs baseline: 1.7881x; 1.7881x over previous
//
#include <hip/hip_runtime.h>

#define IMG_H 8192
#define IMG_W 8192
#define TILE_W 256
#define TILE_H 16
#define ST_ROWS (TILE_H + 2)                 // 18 staged rows
#define ST_COLS 264                          // staged floats/row: image cols X0-4 .. X0+259
#define CHUNKS_PER_ROW (ST_COLS / 4)         // 66 x 16B chunks
#define N_CHUNKS (ST_ROWS * CHUNKS_PER_ROW)  // 1188
#define GRID_X (IMG_W / TILE_W)              // 32
#define GRID_Y (IMG_H / TILE_H)              // 512

typedef float floatx4 __attribute__((ext_vector_type(4)));

__global__ __launch_bounds__(256) void conv3x3_lds(const float* __restrict__ img,
                                                   const float* __restrict__ ker,
                                                   float* __restrict__ out) {
    // Linear LDS: chunk c occupies bytes [c*16, c*16+16) = row c/66, cols 4*(c%66)..+3
    __shared__ float lds[ST_ROWS * ST_COLS];

    const int bx = blockIdx.x & (GRID_X - 1);
    const int by = blockIdx.x >> 5;
    const int X0 = bx * TILE_W;
    const int Y0 = by * TILE_H;
    const int t  = threadIdx.x;

    // ---- stage: 1188 async 16B chunks, clamped addresses (edges fixed up below) ----
    #pragma unroll
    for (int pass = 0; pass < 5; ++pass) {
        const int chunk = pass * 256 + t;
        if (chunk < N_CHUNKS) {
            const int r  = chunk / CHUNKS_PER_ROW;
            const int c4 = chunk % CHUNKS_PER_ROW;
            int gy = Y0 - 1 + r;
            gy = min(max(gy, 0), IMG_H - 1);
            int gx = X0 - 4 + c4 * 4;
            gx = min(max(gx, 0), IMG_W - 4);
            const float* src = img + (size_t)gy * IMG_W + gx;
            float* dst = &lds[chunk * 4];
            __builtin_amdgcn_global_load_lds(
                (const __attribute__((address_space(1))) void*)src,
                (__attribute__((address_space(3))) void*)dst,
                16, 0, 0);
        }
    }
    asm volatile("s_waitcnt vmcnt(0)" ::: "memory");
    __syncthreads();

    // ---- zero-fixup of out-of-image halo cells (block-uniform conditions) ----
    const bool eT = (Y0 == 0), eB = (Y0 == IMG_H - TILE_H);
    const bool eL = (X0 == 0), eR = (X0 == IMG_W - TILE_W);
    if (eT | eB | eL | eR) {
        const floatx4 z = {0.f, 0.f, 0.f, 0.f};
        if (eT && t < CHUNKS_PER_ROW) *(floatx4*)&lds[t * 4] = z;                          // staged row 0 = image row -1
        if (eB && t < CHUNKS_PER_ROW) *(floatx4*)&lds[(ST_ROWS - 1) * ST_COLS + t * 4] = z; // staged row 17 = image row 8192
        if (eL && t < ST_ROWS) *(floatx4*)&lds[t * ST_COLS + 0] = z;                        // staged cols 0..3 = image cols -4..-1
        if (eR && t < ST_ROWS) *(floatx4*)&lds[t * ST_COLS + 260] = z;                      // staged cols 260..263 = image cols 8192..
        __syncthreads();
    }

    // ---- compute: wave w -> output rows 4w..4w+3; lane -> 4 px ----
    const float w00 = ker[0], w01 = ker[1], w02 = ker[2];
    const float w10 = ker[3], w11 = ker[4], w12 = ker[5];
    const float w20 = ker[6], w21 = ker[7], w22 = ker[8];

    const int wv = t >> 6;
    const int ln = t & 63;
    const int oyBase = wv * 4;
    const int colBase = 4 * ln;   // staged col of first output px (image col X0+4ln -> staged col 4ln+4; vL starts at 4ln)

    // three overlapping b128 per row: vL(cols 4ln..+3), vC(+4..+7), vR(+8..+11) — lane stride 16B, conflict-free
    #define LDROW(r, A, B, C) do {                                     \
        const float* p_ = &lds[(r) * ST_COLS + colBase];               \
        A = *(const floatx4*)p_;                                       \
        B = *(const floatx4*)(p_ + 4);                                 \
        C = *(const floatx4*)(p_ + 8);                                 \
    } while (0)

    floatx4 a0, b0, c0, a1, b1, c1;
    LDROW(oyBase + 0, a0, b0, c0);
    LDROW(oyBase + 1, a1, b1, c1);

    #pragma unroll
    for (int oy = 0; oy < 4; ++oy) {
        floatx4 a2, b2, c2;
        LDROW(oyBase + oy + 2, a2, b2, c2);

        // window: staged rows oy..oy+2 = image rows y-1,y,y+1 for y = Y0+oyBase+oy
        float t0[6] = {a0.w, b0.x, b0.y, b0.z, b0.w, c0.x};
        float t1[6] = {a1.w, b1.x, b1.y, b1.z, b1.w, c1.x};
        float t2[6] = {a2.w, b2.x, b2.y, b2.z, b2.w, c2.x};

        floatx4 res;
        #pragma unroll
        for (int j = 0; j < 4; ++j) {
            res[j] = w00 * t0[j] + w01 * t0[j + 1] + w02 * t0[j + 2]
                   + w10 * t1[j] + w11 * t1[j + 1] + w12 * t1[j + 2]
                   + w20 * t2[j] + w21 * t2[j + 1] + w22 * t2[j + 2];
        }

        const int y = Y0 + oyBase + oy;
        __builtin_nontemporal_store(res, (floatx4*)(out + (size_t)y * IMG_W + X0 + colBase));

        a0 = a1; b0 = b1; c0 = c1;
        a1 = a2; b1 = b2; c1 = c2;
    }
    #undef LDROW
}

extern "C" void kernel_launch(void* const* d_in, const int* in_sizes, int n_in,
                              void* d_out, int out_size, void* d_ws, size_t ws_size,
                              hipStream_t stream) {
    const float* img = (const float*)d_in[0];
    const float* ker = (const float*)d_in[1];
    float* out = (float*)d_out;

    const int grid = GRID_X * GRID_Y;   // 16384 blocks; vertical halo-sharing neighbors (b±32) land on the same XCD (32%8==0)
    conv3x3_lds<<<grid, 256, 0, stream>>>(img, ker, out);
}

// Round 6
// 89.937 us; speedup vs baseline: 1.7938x; 1.0032x over previous
//
#include <hip/hip_runtime.h>

#define IMG_H 8192
#define IMG_W 8192
#define TILE_W 256
#define TILE_H 32
#define ST_ROWS (TILE_H + 2)                 // 34 staged rows
#define ST_COLS 264                          // staged floats/row: image cols X0-4 .. X0+259
#define CHUNKS_PER_ROW (ST_COLS / 4)         // 66 x 16B chunks
#define N_CHUNKS (ST_ROWS * CHUNKS_PER_ROW)  // 2244
#define GRID_X (IMG_W / TILE_W)              // 32
#define GRID_Y (IMG_H / TILE_H)              // 256

typedef float floatx4 __attribute__((ext_vector_type(4)));

__global__ __launch_bounds__(256) void conv3x3_lds(const float* __restrict__ img,
                                                   const float* __restrict__ ker,
                                                   float* __restrict__ out) {
    // Linear LDS: chunk c occupies bytes [c*16, c*16+16) = row c/66, cols 4*(c%66)..+3
    __shared__ float lds[ST_ROWS * ST_COLS];   // 35,904 B -> 4 blocks/CU

    const int bx = blockIdx.x & (GRID_X - 1);
    const int by = blockIdx.x >> 5;
    const int X0 = bx * TILE_W;
    const int Y0 = by * TILE_H;
    const int t  = threadIdx.x;

    // ---- stage: 2244 async 16B chunks, clamped addresses (edges fixed up below) ----
    #pragma unroll
    for (int pass = 0; pass < 9; ++pass) {
        const int chunk = pass * 256 + t;
        if (chunk < N_CHUNKS) {
            const int r  = chunk / CHUNKS_PER_ROW;
            const int c4 = chunk % CHUNKS_PER_ROW;
            int gy = Y0 - 1 + r;
            gy = min(max(gy, 0), IMG_H - 1);
            int gx = X0 - 4 + c4 * 4;
            gx = min(max(gx, 0), IMG_W - 4);
            const float* src = img + (size_t)gy * IMG_W + gx;
            float* dst = &lds[chunk * 4];
            __builtin_amdgcn_global_load_lds(
                (const __attribute__((address_space(1))) void*)src,
                (__attribute__((address_space(3))) void*)dst,
                16, 0, 0);
        }
    }
    asm volatile("s_waitcnt vmcnt(0)" ::: "memory");
    __syncthreads();

    // ---- zero-fixup of out-of-image halo cells (block-uniform conditions) ----
    const bool eT = (Y0 == 0), eB = (Y0 == IMG_H - TILE_H);
    const bool eL = (X0 == 0), eR = (X0 == IMG_W - TILE_W);
    if (eT | eB | eL | eR) {
        const floatx4 z = {0.f, 0.f, 0.f, 0.f};
        if (eT && t < CHUNKS_PER_ROW) *(floatx4*)&lds[t * 4] = z;                           // staged row 0 = image row -1
        if (eB && t < CHUNKS_PER_ROW) *(floatx4*)&lds[(ST_ROWS - 1) * ST_COLS + t * 4] = z; // staged row 33 = image row 8192
        if (eL && t < ST_ROWS) *(floatx4*)&lds[t * ST_COLS + 0] = z;                        // staged cols 0..3 = image cols -4..-1
        if (eR && t < ST_ROWS) *(floatx4*)&lds[t * ST_COLS + 260] = z;                      // staged cols 260..263 = image cols 8192..
        __syncthreads();
    }

    // ---- compute: wave w -> output rows 8w..8w+7; lane -> 4 px ----
    const float w00 = ker[0], w01 = ker[1], w02 = ker[2];
    const float w10 = ker[3], w11 = ker[4], w12 = ker[5];
    const float w20 = ker[6], w21 = ker[7], w22 = ker[8];

    const int wv = t >> 6;
    const int ln = t & 63;
    const int oyBase = wv * 8;
    const int colBase = 4 * ln;   // staged col of first output px's left neighbor block

    // three overlapping b128 per row: vL(cols 4ln..+3), vC(+4..+7), vR(+8..+11) — lane stride 16B, conflict-free
    #define LDROW(r, A, B, C) do {                                     \
        const float* p_ = &lds[(r) * ST_COLS + colBase];               \
        A = *(const floatx4*)p_;                                       \
        B = *(const floatx4*)(p_ + 4);                                 \
        C = *(const floatx4*)(p_ + 8);                                 \
    } while (0)

    floatx4 a0, b0, c0, a1, b1, c1;
    LDROW(oyBase + 0, a0, b0, c0);
    LDROW(oyBase + 1, a1, b1, c1);

    #pragma unroll
    for (int oy = 0; oy < 8; ++oy) {
        floatx4 a2, b2, c2;
        LDROW(oyBase + oy + 2, a2, b2, c2);

        // window: staged rows oy..oy+2 = image rows y-1,y,y+1 for y = Y0+oyBase+oy
        float t0[6] = {a0.w, b0.x, b0.y, b0.z, b0.w, c0.x};
        float t1[6] = {a1.w, b1.x, b1.y, b1.z, b1.w, c1.x};
        float t2[6] = {a2.w, b2.x, b2.y, b2.z, b2.w, c2.x};

        floatx4 res;
        #pragma unroll
        for (int j = 0; j < 4; ++j) {
            res[j] = w00 * t0[j] + w01 * t0[j + 1] + w02 * t0[j + 2]
                   + w10 * t1[j] + w11 * t1[j + 1] + w12 * t1[j + 2]
                   + w20 * t2[j] + w21 * t2[j + 1] + w22 * t2[j + 2];
        }

        const int y = Y0 + oyBase + oy;
        __builtin_nontemporal_store(res, (floatx4*)(out + (size_t)y * IMG_W + X0 + colBase));

        a0 = a1; b0 = b1; c0 = c1;
        a1 = a2; b1 = b2; c1 = c2;
    }
    #undef LDROW
}

extern "C" void kernel_launch(void* const* d_in, const int* in_sizes, int n_in,
                              void* d_out, int out_size, void* d_ws, size_t ws_size,
                              hipStream_t stream) {
    const float* img = (const float*)d_in[0];
    const float* ker = (const float*)d_in[1];
    float* out = (float*)d_out;

    const int grid = GRID_X * GRID_Y;   // 8192 blocks; vertical halo-sharing neighbors (b±32) land on the same XCD (32%8==0)
    conv3x3_lds<<<grid, 256, 0, stream>>>(img, ker, out);
}